// Round 8
// baseline (287.958 us; speedup 1.0000x reference)
//
#include <hip/hip_runtime.h>
#include <hip/hip_bf16.h>
#include <math.h>

typedef __bf16 bf16x8 __attribute__((ext_vector_type(8)));
typedef float  f32x4  __attribute__((ext_vector_type(4)));

// 8-byte float pair with 4-byte alignment (gather pair loads)
struct __attribute__((packed, aligned(4))) F2 { float x, y; };

#define BB 2
#define C1 256
#define C2 256
#define HH 64
#define WW 64
#define HW 4096
#define OCH 27
#define EPSV 1e-5f

// workspace layout (bytes)
#define OM_OFF   0u          // 221184 f32 = 884736 B
#define WBF_OFF  884736u     // 589824 bf16 = 1179648 B
#define WOFF_OFF 2064384u    // 73728 bf16 = 147456 B  (total ~2.2 MB)

// ---------------------------------------------------------------------------
// Kernel A: w_dcn fp32 [o][c*9+k] -> bf16 k-major [o][k*256+c].
// ---------------------------------------------------------------------------
__global__ __launch_bounds__(256) void wprep_kernel(
    const float* __restrict__ w, __bf16* __restrict__ wbfT)
{
    int t = blockIdx.x * 256 + threadIdx.x;    // < 589824
    int o = t / 2304;
    int r = t - o * 2304;
    int k = r >> 8;
    int c = r & 255;
    wbfT[t] = (__bf16)w[o * 2304 + c * 9 + k];
}

// ---------------------------------------------------------------------------
// Kernel A2: w_off [oc][ic][k] -> bf16 k-major [32 padded oc][k*256+c].
// ---------------------------------------------------------------------------
__global__ __launch_bounds__(256) void wprep_off_kernel(
    const float* __restrict__ w_off, __bf16* __restrict__ woffB)
{
    int t = blockIdx.x * 256 + threadIdx.x;    // < 73728
    int o = t / 2304;
    int r = t - o * 2304;
    int k = r >> 8;
    int c = r & 255;
    woffB[t] = (o < OCH) ? (__bf16)w_off[o * 2304 + c * 9 + k] : (__bf16)0.f;
}

// ---------------------------------------------------------------------------
// Kernel B: offset conv via MFMA im2col. M=16 pixels, grid 512 (2 blocks/CU).
// K=2304 split 4 ways across waves (9 chunks of 64). Barrier-free main loop;
// one LDS reduction at the end.
// ---------------------------------------------------------------------------
__global__ __launch_bounds__(256) void offset_mfma_kernel(
    const float* __restrict__ x, const __bf16* __restrict__ woffB,
    const float* __restrict__ b_off, float* __restrict__ om)
{
    __shared__ float sD[4][16][33];            // 8.4 KB

    const int tid = threadIdx.x, wv = tid >> 6, lane = tid & 63;
    const int g = (blockIdx.x & 7) * 64 + (blockIdx.x >> 3);   // XCD swizzle
    const int pixBase = g * 16;
    const int b = pixBase >> 12;
    const int hwBase = pixBase & 4095;
    const int h = hwBase >> 6, w0 = hwBase & 63;
    const int n15 = lane & 15, q4 = lane >> 4;

    f32x4 acc[2];
    #pragma unroll
    for (int j = 0; j < 2; j++) acc[j] = (f32x4){0.f, 0.f, 0.f, 0.f};

    const float* xb = x + ((size_t)b * C1 << 12);

    for (int i = 0; i < 9; i++) {
        const int kb = wv * 9 + i;             // chunk in [0,36)
        const int k = kb >> 2, cc = kb & 3;
        const int kh = k / 3, kw = k % 3;
        const int hh = h + kh - 1;
        const bool vh = (hh >= 0) && (hh < HH);
        const int hc = min(max(hh, 0), HH - 1);

        const int ww = w0 + n15 + kw - 1;
        const bool valid = vh && (ww >= 0) && (ww < WW);
        const int wc = min(max(ww, 0), WW - 1);
        const float* src = xb + hc * WW + wc;

        bf16x8 af[2];
        #pragma unroll
        for (int ks = 0; ks < 2; ks++) {
            bf16x8 a;
            #pragma unroll
            for (int j = 0; j < 8; j++) {
                int c = cc * 64 + q4 * 8 + ks * 32 + j;
                float v = src[(size_t)c << 12];
                a[j] = (__bf16)(valid ? v : 0.f);
            }
            af[ks] = a;
        }

        const __bf16* bp = woffB + k * 256 + cc * 64 + q4 * 8;
        #pragma unroll
        for (int nf = 0; nf < 2; nf++) {
            #pragma unroll
            for (int ks = 0; ks < 2; ks++) {
                bf16x8 bfr = *(const bf16x8*)(bp + (size_t)(nf * 16 + n15) * 2304 + ks * 32);
                acc[nf] = __builtin_amdgcn_mfma_f32_16x16x32_bf16(
                    af[ks], bfr, acc[nf], 0, 0, 0);
            }
        }
    }

    #pragma unroll
    for (int nf = 0; nf < 2; nf++)
        #pragma unroll
        for (int r = 0; r < 4; r++)
            sD[wv][q4 * 4 + r][nf * 16 + n15] = acc[nf][r];
    __syncthreads();

    for (int t = tid; t < OCH * 16; t += 256) {
        int oc = t >> 4, m = t & 15;
        float s = b_off[oc] + sD[0][m][oc] + sD[1][m][oc] + sD[2][m][oc] + sD[3][m][oc];
        om[(size_t)b * OCH * HW + oc * HW + hwBase + m] = s;
    }
}

// ---------------------------------------------------------------------------
// Kernel C: FUSED gather + MFMA GEMM + BN + SiLU. Barrier-free main loop.
// M=16 pixels, N=256, grid 512 (2 blocks/CU = 8 waves/CU). Each wave owns an
// N-slice of 64 and runs ALL 36 K-chunks, gathering its own A-fragments
// directly into registers (2 coalesced 8B pair-loads + 4 FMA per value,
// pre-permuted weights from phase 0). A-gather is 4x redundant across waves
// but the per-chunk x window (~16 KB) is L1-resident. B fragments load
// global->VGPR from L2-resident wbfT. acc = 16 VGPRs/wave.
// ---------------------------------------------------------------------------
__global__ __launch_bounds__(256) void fused_kernel(
    const float* __restrict__ x, const float* __restrict__ om,
    const __bf16* __restrict__ wbfT,
    const float* __restrict__ gamma, const float* __restrict__ beta,
    const float* __restrict__ rmean, const float* __restrict__ rvar,
    float* __restrict__ out)
{
    __shared__ int    sOff[9][16][2];    // 1.1 KB
    __shared__ float4 sWt4[9][16];       // 2.3 KB

    const int tid = threadIdx.x, wv = tid >> 6, lane = tid & 63;
    const int g = (blockIdx.x & 7) * 64 + (blockIdx.x >> 3);   // XCD swizzle
    const int pixBase = g * 16;
    const int b = pixBase >> 12;
    const int hwBase = pixBase & 4095;
    const int h = hwBase >> 6, w0 = hwBase & 63;

    // --- Phase 0: per (pixel,tap) pair offsets + pre-permuted weights ---
    const float* omb = om + (size_t)b * OCH * HW;
    if (tid < 144) {
        int k = tid >> 4, p = tid & 15;
        int hw = hwBase + p;
        float dy  = omb[(2 * k) * HW + hw];
        float dx  = omb[(2 * k + 1) * HW + hw];
        float mm  = omb[(18 + k) * HW + hw];
        mm = 1.f / (1.f + __expf(-mm));
        float py = (float)(h - 1 + k / 3) + dy;
        float px = (float)(w0 + p - 1 + k % 3) + dx;
        float y0f = floorf(py), x0f = floorf(px);
        float ly = py - y0f, lx = px - x0f;
        int y0 = (int)y0f, x0 = (int)x0f;
        int r0 = min(max(y0, 0), HH - 1);
        int r1 = min(max(y0 + 1, 0), HH - 1);
        float vy0 = (y0 >= 0 && y0 < HH) ? 1.f : 0.f;
        float vy1 = (y0 + 1 >= 0 && y0 + 1 < HH) ? 1.f : 0.f;
        int xa = min(max(x0, 0), WW - 2);
        float ex0 = (x0 >= 0 && x0 < WW) ? (1.f - lx) : 0.f;
        float ex1 = (x0 + 1 >= 0 && x0 + 1 < WW) ? lx : 0.f;
        int d = x0 - xa;                 // -1 / 0 / +1 (clamped cases)
        float E0, E1;
        if (d == 0)      { E0 = ex0; E1 = ex1; }
        else if (d > 0)  { E0 = 0.f; E1 = ex0; }
        else             { E0 = ex1; E1 = 0.f; }
        float m0 = (1.f - ly) * vy0 * mm, m1 = ly * vy1 * mm;
        sOff[k][p][0] = (r0 * WW + xa) * 4;
        sOff[k][p][1] = (r1 * WW + xa) * 4;
        sWt4[k][p] = (float4){E0 * m0, E1 * m0, E0 * m1, E1 * m1};
    }
    __syncthreads();

    const int n15 = lane & 15, q4 = lane >> 4;

    f32x4 acc[4];
    #pragma unroll
    for (int j = 0; j < 4; j++) acc[j] = (f32x4){0.f, 0.f, 0.f, 0.f};

    const char* xb = (const char*)x + ((size_t)b * C1 << 14);
    const __bf16* bw = wbfT + (size_t)(wv * 64 + n15) * 2304;

    for (int kb = 0; kb < 36; kb++) {
        const int k = kb >> 2, cc = kb & 3;
        const int2   O = *(const int2*)&sOff[k][n15][0];
        const float4 W = sWt4[k][n15];

        // --- gather A-fragment: lane (q4,n15) owns pixel n15, ch q4*8+... ---
        const char* cb0 = xb + ((size_t)(cc * 64 + q4 * 8) << 14);
        bf16x8 af[2];
        #pragma unroll
        for (int ks = 0; ks < 2; ks++) {
            bf16x8 a;
            #pragma unroll
            for (int j = 0; j < 8; j++) {
                const char* cb = cb0 + ((size_t)(ks * 32 + j) << 14);
                F2 p0 = *(const F2*)(cb + O.x);
                F2 p1 = *(const F2*)(cb + O.y);
                a[j] = (__bf16)(W.x * p0.x + W.y * p0.y
                              + W.z * p1.x + W.w * p1.y);
            }
            af[ks] = a;
        }

        // --- B fragments global->VGPR, MFMA ---
        const __bf16* bp = bw + k * 256 + cc * 64 + q4 * 8;
        #pragma unroll
        for (int nf = 0; nf < 4; nf++) {
            #pragma unroll
            for (int ks = 0; ks < 2; ks++) {
                bf16x8 bfr = *(const bf16x8*)(bp + (size_t)nf * 16 * 2304 + ks * 32);
                acc[nf] = __builtin_amdgcn_mfma_f32_16x16x32_bf16(
                    af[ks], bfr, acc[nf], 0, 0, 0);
            }
        }
    }

    // --- Epilogue: BN + SiLU (C/D layout: col=o, row=pixel) ---
    #pragma unroll
    for (int nf = 0; nf < 4; nf++) {
        int o = wv * 64 + nf * 16 + n15;
        float inv = gamma[o] * rsqrtf(rvar[o] + EPSV);
        float sh = beta[o] - rmean[o] * inv;
        #pragma unroll
        for (int r = 0; r < 4; r++) {
            int m = q4 * 4 + r;
            float y = acc[nf][r] * inv + sh;
            out[(size_t)((b * C2 + o) << 12) + hwBase + m]
                = y * (1.f / (1.f + __expf(-y)));
        }
    }
}

// ---------------------------------------------------------------------------
extern "C" void kernel_launch(void* const* d_in, const int* in_sizes, int n_in,
                              void* d_out, int out_size, void* d_ws, size_t ws_size,
                              hipStream_t stream) {
    const float* x      = (const float*)d_in[0];
    const float* w_off  = (const float*)d_in[1];
    const float* b_off  = (const float*)d_in[2];
    const float* w_dcn  = (const float*)d_in[3];
    const float* gamma  = (const float*)d_in[4];
    const float* beta   = (const float*)d_in[5];
    const float* rmean  = (const float*)d_in[6];
    const float* rvar   = (const float*)d_in[7];
    float* out = (float*)d_out;

    char* ws = (char*)d_ws;
    float*  om    = (float*)(ws + OM_OFF);
    __bf16* wbfT  = (__bf16*)(ws + WBF_OFF);
    __bf16* woffB = (__bf16*)(ws + WOFF_OFF);

    wprep_kernel<<<2304, 256, 0, stream>>>(w_dcn, wbfT);
    wprep_off_kernel<<<288, 256, 0, stream>>>(w_off, woffB);
    offset_mfma_kernel<<<512, 256, 0, stream>>>(x, woffB, b_off, om);
    fused_kernel<<<512, 256, 0, stream>>>(x, om, wbfT, gamma, beta,
                                          rmean, rvar, out);
}

// Round 9
// 148.906 us; speedup vs baseline: 1.9338x; 1.9338x over previous
//
#include <hip/hip_runtime.h>
#include <hip/hip_bf16.h>
#include <math.h>

typedef __bf16 bf16x8 __attribute__((ext_vector_type(8)));
typedef __bf16 bf16x4 __attribute__((ext_vector_type(4)));
typedef float  f32x4  __attribute__((ext_vector_type(4)));

// 8-byte float pair with 4-byte alignment (gather pair loads)
struct __attribute__((packed, aligned(4))) F2 { float x, y; };

#define BB 2
#define C1 256
#define C2 256
#define HH 64
#define WW 64
#define HW 4096
#define OCH 27
#define EPSV 1e-5f

// workspace layout (bytes)
#define OM_OFF   0u          // 221184 f32 = 884736 B
#define WBF_OFF  884736u     // 589824 bf16 (frag-ordered) = 1179648 B
#define WOFF_OFF 2064384u    // 73728 bf16 (frag-ordered) = 147456 B

// ---------------------------------------------------------------------------
// Kernel A: w_dcn -> fragment-ordered bf16 wbfS.
// wbfS[(((kb*2+ks)*16 + nb)*64 + lane)*8 + j] = w[o][c*9+ktap]
//   o = nb*16 + (lane&15); K = kb*64 + ks*32 + ((lane>>4)&3)*8 + j;
//   c = K&255; ktap = K>>8  (tap-major K ordering).
// In the GEMM, a B-fragment load is then 64 lanes x 16 B contiguous.
// ---------------------------------------------------------------------------
__global__ __launch_bounds__(256) void wprep_kernel(
    const float* __restrict__ w, __bf16* __restrict__ wbfS)
{
    int t = blockIdx.x * 256 + threadIdx.x;    // < 73728
    int l = t & 63;
    int nb = (t >> 6) & 15;
    int ks = (t >> 10) & 1;
    int kb = t >> 11;                          // 0..35
    int o = nb * 16 + (l & 15);
    int kq = (l >> 4) & 3;
    bf16x8 v;
    #pragma unroll
    for (int j = 0; j < 8; j++) {
        int K = kb * 64 + ks * 32 + kq * 8 + j;
        v[j] = (__bf16)w[o * 2304 + (K & 255) * 9 + (K >> 8)];
    }
    *(bf16x8*)(wbfS + (size_t)t * 8) = v;
}

// ---------------------------------------------------------------------------
// Kernel A2: w_off -> fragment-ordered bf16 woffS (N padded 27->32).
// woffS[(((kb*2+ks)*2 + nf)*64 + lane)*8 + j]
// ---------------------------------------------------------------------------
__global__ __launch_bounds__(256) void wprep_off_kernel(
    const float* __restrict__ w_off, __bf16* __restrict__ woffS)
{
    int t = blockIdx.x * 256 + threadIdx.x;    // < 9216
    int l = t & 63;
    int nf = (t >> 6) & 1;
    int ks = (t >> 7) & 1;
    int kb = t >> 8;                           // 0..35
    int o = nf * 16 + (l & 15);
    int kq = (l >> 4) & 3;
    bf16x8 v;
    #pragma unroll
    for (int j = 0; j < 8; j++) {
        int K = kb * 64 + ks * 32 + kq * 8 + j;
        v[j] = (o < OCH) ? (__bf16)w_off[o * 2304 + (K & 255) * 9 + (K >> 8)]
                         : (__bf16)0.f;
    }
    *(bf16x8*)(woffS + (size_t)t * 8) = v;
}

// ---------------------------------------------------------------------------
// Kernel B: offset conv via MFMA im2col. M=16 pixels, grid 512 (2 blocks/CU).
// K-split 4 ways across waves, barrier-free; B loads are frag-ordered
// coalesced (fixes r8's 16-line divergence); one LDS reduction at the end.
// ---------------------------------------------------------------------------
__global__ __launch_bounds__(256) void offset_mfma_kernel(
    const float* __restrict__ x, const __bf16* __restrict__ woffS,
    const float* __restrict__ b_off, float* __restrict__ om)
{
    __shared__ float sD[4][16][33];            // 8.4 KB

    const int tid = threadIdx.x, wv = tid >> 6, lane = tid & 63;
    const int g = (blockIdx.x & 7) * 64 + (blockIdx.x >> 3);   // XCD swizzle
    const int pixBase = g * 16;
    const int b = pixBase >> 12;
    const int hwBase = pixBase & 4095;
    const int h = hwBase >> 6, w0 = hwBase & 63;
    const int n15 = lane & 15, q4 = lane >> 4;

    f32x4 acc[2];
    #pragma unroll
    for (int j = 0; j < 2; j++) acc[j] = (f32x4){0.f, 0.f, 0.f, 0.f};

    const float* xb = x + ((size_t)b * C1 << 12);

    for (int i = 0; i < 9; i++) {
        const int kb = wv * 9 + i;             // chunk in [0,36)
        const int k = kb >> 2, cc = kb & 3;
        const int kh = k / 3, kw = k % 3;
        const int hh = h + kh - 1;
        const bool vh = (hh >= 0) && (hh < HH);
        const int hc = min(max(hh, 0), HH - 1);

        const int ww = w0 + n15 + kw - 1;
        const bool valid = vh && (ww >= 0) && (ww < WW);
        const int wc = min(max(ww, 0), WW - 1);
        const float* src = xb + hc * WW + wc;

        bf16x8 af[2];
        #pragma unroll
        for (int ks = 0; ks < 2; ks++) {
            bf16x8 a;
            #pragma unroll
            for (int j = 0; j < 8; j++) {
                int c = cc * 64 + q4 * 8 + ks * 32 + j;
                float v = src[(size_t)c << 12];
                a[j] = (__bf16)(valid ? v : 0.f);
            }
            af[ks] = a;
        }

        // frag-ordered B: contiguous 1 KB per (kb,ks,nf)
        #pragma unroll
        for (int nf = 0; nf < 2; nf++) {
            #pragma unroll
            for (int ks = 0; ks < 2; ks++) {
                bf16x8 bfr = *(const bf16x8*)(woffS
                    + ((size_t)(((kb * 2 + ks) * 2 + nf) * 64 + lane)) * 8);
                acc[nf] = __builtin_amdgcn_mfma_f32_16x16x32_bf16(
                    af[ks], bfr, acc[nf], 0, 0, 0);
            }
        }
    }

    #pragma unroll
    for (int nf = 0; nf < 2; nf++)
        #pragma unroll
        for (int r = 0; r < 4; r++)
            sD[wv][q4 * 4 + r][nf * 16 + n15] = acc[nf][r];
    __syncthreads();

    for (int t = tid; t < OCH * 16; t += 256) {
        int oc = t >> 4, m = t & 15;
        float s = b_off[oc] + sD[0][m][oc] + sD[1][m][oc] + sD[2][m][oc] + sD[3][m][oc];
        om[(size_t)b * OCH * HW + oc * HW + hwBase + m] = s;
    }
}

// ---------------------------------------------------------------------------
// Kernel C: FUSED gather + MFMA GEMM + BN + SiLU.
// M=16 pixels x N=256, grid 512 (2 blocks/CU for latency overlap).
// Shared sA gather (no duplication; pixel-coherent F2 pair loads), ONE
// barrier per chunk (sA double-buffered). B fragments load global->VGPR
// from fragment-ordered wbfS: 64 lanes x 16 B contiguous. LDS ~8 KB.
// ---------------------------------------------------------------------------
__global__ __launch_bounds__(256) void fused_kernel(
    const float* __restrict__ x, const float* __restrict__ om,
    const __bf16* __restrict__ wbfS,
    const float* __restrict__ gamma, const float* __restrict__ beta,
    const float* __restrict__ rmean, const float* __restrict__ rvar,
    float* __restrict__ out)
{
    __shared__ __bf16 sA[2][16 * 72];    // 4.6 KB (row stride 72)
    __shared__ int    sOff[9][16][2];    // 1.1 KB
    __shared__ float4 sWt4[9][16];       // 2.3 KB

    const int tid = threadIdx.x, wv = tid >> 6, lane = tid & 63;
    const int g = (blockIdx.x & 7) * 64 + (blockIdx.x >> 3);   // XCD swizzle
    const int pixBase = g * 16;
    const int b = pixBase >> 12;
    const int hwBase = pixBase & 4095;
    const int h = hwBase >> 6, w0 = hwBase & 63;

    // --- Phase 0: per (pixel,tap) pair offsets + pre-permuted weights ---
    const float* omb = om + (size_t)b * OCH * HW;
    if (tid < 144) {
        int k = tid >> 4, p = tid & 15;
        int hw = hwBase + p;
        float dy  = omb[(2 * k) * HW + hw];
        float dx  = omb[(2 * k + 1) * HW + hw];
        float mm  = omb[(18 + k) * HW + hw];
        mm = 1.f / (1.f + __expf(-mm));
        float py = (float)(h - 1 + k / 3) + dy;
        float px = (float)(w0 + p - 1 + k % 3) + dx;
        float y0f = floorf(py), x0f = floorf(px);
        float ly = py - y0f, lx = px - x0f;
        int y0 = (int)y0f, x0 = (int)x0f;
        int r0 = min(max(y0, 0), HH - 1);
        int r1 = min(max(y0 + 1, 0), HH - 1);
        float vy0 = (y0 >= 0 && y0 < HH) ? 1.f : 0.f;
        float vy1 = (y0 + 1 >= 0 && y0 + 1 < HH) ? 1.f : 0.f;
        int xa = min(max(x0, 0), WW - 2);
        float ex0 = (x0 >= 0 && x0 < WW) ? (1.f - lx) : 0.f;
        float ex1 = (x0 + 1 >= 0 && x0 + 1 < WW) ? lx : 0.f;
        int d = x0 - xa;
        float E0, E1;
        if (d == 0)      { E0 = ex0; E1 = ex1; }
        else if (d > 0)  { E0 = 0.f; E1 = ex0; }
        else             { E0 = ex1; E1 = 0.f; }
        float m0 = (1.f - ly) * vy0 * mm, m1 = ly * vy1 * mm;
        sOff[k][p][0] = (r0 * WW + xa) * 4;
        sOff[k][p][1] = (r1 * WW + xa) * 4;
        sWt4[k][p] = (float4){E0 * m0, E1 * m0, E0 * m1, E1 * m1};
    }
    __syncthreads();

    const int gp = tid & 15;             // gather pixel
    const int cg = tid >> 4;             // gather channel group (4 ch each)
    const int n15 = lane & 15, q4 = lane >> 4;

    f32x4 acc[4];
    #pragma unroll
    for (int j = 0; j < 4; j++) acc[j] = (f32x4){0.f, 0.f, 0.f, 0.f};

    const char* xb = (const char*)x + ((size_t)b * C1 << 14);

    for (int kb = 0; kb < 36; kb++) {
        const int k = kb >> 2, cc = kb & 3;

        // --- B fragments: coalesced contiguous loads from frag-ordered wbfS
        bf16x8 bfr[4][2];
        #pragma unroll
        for (int nf = 0; nf < 4; nf++)
            #pragma unroll
            for (int ks = 0; ks < 2; ks++)
                bfr[nf][ks] = *(const bf16x8*)(wbfS
                    + ((size_t)(((kb * 2 + ks) * 16 + wv * 4 + nf) * 64 + lane)) * 8);

        // --- gather 4 channels for pixel gp -> sA[kb&1] ---
        {
            const int2   O = *(const int2*)&sOff[k][gp][0];
            const float4 W = sWt4[k][gp];
            const char* cb0 = xb + ((size_t)(cc * 64 + cg * 4) << 14);
            bf16x4 v4;
            #pragma unroll
            for (int j = 0; j < 4; j++) {
                const char* cb = cb0 + ((size_t)j << 14);
                F2 p0 = *(const F2*)(cb + O.x);
                F2 p1 = *(const F2*)(cb + O.y);
                v4[j] = (__bf16)(W.x * p0.x + W.y * p0.y
                               + W.z * p1.x + W.w * p1.y);
            }
            *(bf16x4*)&sA[kb & 1][gp * 72 + cg * 4] = v4;
        }
        __syncthreads();

        // --- A fragments from LDS, MFMA ---
        bf16x8 af[2];
        #pragma unroll
        for (int ks = 0; ks < 2; ks++)
            af[ks] = *(const bf16x8*)&sA[kb & 1][n15 * 72 + ks * 32 + q4 * 8];
        #pragma unroll
        for (int nf = 0; nf < 4; nf++)
            #pragma unroll
            for (int ks = 0; ks < 2; ks++)
                acc[nf] = __builtin_amdgcn_mfma_f32_16x16x32_bf16(
                    af[ks], bfr[nf][ks], acc[nf], 0, 0, 0);
        // no second barrier: sA double-buffered (see r7 safety argument)
    }

    // --- Epilogue: BN + SiLU; lane stores float4 (4 consecutive pixels) ---
    #pragma unroll
    for (int nf = 0; nf < 4; nf++) {
        int o = wv * 64 + nf * 16 + n15;
        float inv = gamma[o] * rsqrtf(rvar[o] + EPSV);
        float sh = beta[o] - rmean[o] * inv;
        f32x4 y4;
        #pragma unroll
        for (int r = 0; r < 4; r++) {
            float y = acc[nf][r] * inv + sh;
            y4[r] = y * (1.f / (1.f + __expf(-y)));
        }
        *(f32x4*)(out + (size_t)((b * C2 + o) << 12) + hwBase + q4 * 4) = y4;
    }
}

// ---------------------------------------------------------------------------
extern "C" void kernel_launch(void* const* d_in, const int* in_sizes, int n_in,
                              void* d_out, int out_size, void* d_ws, size_t ws_size,
                              hipStream_t stream) {
    const float* x      = (const float*)d_in[0];
    const float* w_off  = (const float*)d_in[1];
    const float* b_off  = (const float*)d_in[2];
    const float* w_dcn  = (const float*)d_in[3];
    const float* gamma  = (const float*)d_in[4];
    const float* beta   = (const float*)d_in[5];
    const float* rmean  = (const float*)d_in[6];
    const float* rvar   = (const float*)d_in[7];
    float* out = (float*)d_out;

    char* ws = (char*)d_ws;
    float*  om    = (float*)(ws + OM_OFF);
    __bf16* wbfS  = (__bf16*)(ws + WBF_OFF);
    __bf16* woffS = (__bf16*)(ws + WOFF_OFF);

    wprep_kernel<<<288, 256, 0, stream>>>(w_dcn, wbfS);
    wprep_off_kernel<<<36, 256, 0, stream>>>(w_off, woffS);
    offset_mfma_kernel<<<512, 256, 0, stream>>>(x, woffS, b_off, om);
    fused_kernel<<<512, 256, 0, stream>>>(x, om, wbfS, gamma, beta,
                                          rmean, rvar, out);
}

// Round 10
// 129.039 us; speedup vs baseline: 2.2316x; 1.1540x over previous
//
#include <hip/hip_runtime.h>
#include <hip/hip_bf16.h>
#include <math.h>

typedef __bf16 bf16x8 __attribute__((ext_vector_type(8)));
typedef float  f32x4  __attribute__((ext_vector_type(4)));

#define BB 2
#define C1 256
#define C2 256
#define HH 64
#define WW 64
#define HW 4096
#define OCH 27
#define EPSV 1e-5f

// workspace layout (bytes)
#define OM_OFF   0u          // 221184 f32 = 884736 B
#define WBF_OFF  884736u     // 589824 bf16 (frag-ordered)
#define WOFF_OFF 2064384u    // 73728 bf16 (frag-ordered)
#define XT_OFF   2211840u    // 2*4096*256 bf16 = 4194304 B (HWC)

// ---------------------------------------------------------------------------
// Kernel X: x [b][c][hw] fp32 -> xT [b][hw][c] bf16 (LDS tile transpose).
// Grid 512 = 2(b) x 64(hw-tile 64) x 4(c-tile 64).
// ---------------------------------------------------------------------------
__global__ __launch_bounds__(256) void xprep_kernel(
    const float* __restrict__ x, __bf16* __restrict__ xT)
{
    __shared__ __bf16 tile[64][72];      // [hw_local][c_local], 16B-aligned rows

    const int bt = blockIdx.x;
    const int b = bt >> 8;
    const int ht = (bt & 255) >> 2;
    const int ct = bt & 3;
    const int tid = threadIdx.x;

    const int hw_l = tid & 63, cg = tid >> 6;
    const float* src = x + ((size_t)(b * 256 + ct * 64 + cg * 16) << 12) + ht * 64 + hw_l;
    #pragma unroll
    for (int i = 0; i < 16; i++)
        tile[hw_l][cg * 16 + i] = (__bf16)src[(size_t)i << 12];
    __syncthreads();

    const int hw_o = tid >> 2, cq = tid & 3;
    __bf16* dst = xT + ((size_t)(b * HW + ht * 64 + hw_o) << 8) + ct * 64 + cq * 16;
    *(bf16x8*)dst       = *(const bf16x8*)&tile[hw_o][cq * 16];
    *(bf16x8*)(dst + 8) = *(const bf16x8*)&tile[hw_o][cq * 16 + 8];
}

// ---------------------------------------------------------------------------
// Kernel A: w_dcn -> fragment-ordered bf16 wbfS (unchanged from r9).
// wbfS[(((kb*2+ks)*16 + nb)*64 + lane)*8 + j]; K tap-major.
// ---------------------------------------------------------------------------
__global__ __launch_bounds__(256) void wprep_kernel(
    const float* __restrict__ w, __bf16* __restrict__ wbfS)
{
    int t = blockIdx.x * 256 + threadIdx.x;    // < 73728
    int l = t & 63;
    int nb = (t >> 6) & 15;
    int ks = (t >> 10) & 1;
    int kb = t >> 11;
    int o = nb * 16 + (l & 15);
    int kq = (l >> 4) & 3;
    bf16x8 v;
    #pragma unroll
    for (int j = 0; j < 8; j++) {
        int K = kb * 64 + ks * 32 + kq * 8 + j;
        v[j] = (__bf16)w[o * 2304 + (K & 255) * 9 + (K >> 8)];
    }
    *(bf16x8*)(wbfS + (size_t)t * 8) = v;
}

// ---------------------------------------------------------------------------
// Kernel A2: w_off -> fragment-ordered bf16 woffS (N padded 27->32).
// ---------------------------------------------------------------------------
__global__ __launch_bounds__(256) void wprep_off_kernel(
    const float* __restrict__ w_off, __bf16* __restrict__ woffS)
{
    int t = blockIdx.x * 256 + threadIdx.x;    // < 9216
    int l = t & 63;
    int nf = (t >> 6) & 1;
    int ks = (t >> 7) & 1;
    int kb = t >> 8;
    int o = nf * 16 + (l & 15);
    int kq = (l >> 4) & 3;
    bf16x8 v;
    #pragma unroll
    for (int j = 0; j < 8; j++) {
        int K = kb * 64 + ks * 32 + kq * 8 + j;
        v[j] = (o < OCH) ? (__bf16)w_off[o * 2304 + (K & 255) * 9 + (K >> 8)]
                         : (__bf16)0.f;
    }
    *(bf16x8*)(woffS + (size_t)t * 8) = v;
}

// ---------------------------------------------------------------------------
// Kernel B: offset conv via MFMA im2col from HWC-bf16 xT.
// M=16 px, grid 512 (2 blocks/CU), 4-wave K-split, barrier-free main loop.
// A fragment = TWO contiguous 16B loads per chunk (was 32 scalar fp32 loads).
// ---------------------------------------------------------------------------
__global__ __launch_bounds__(256) void offset_mfma_kernel(
    const __bf16* __restrict__ xT, const __bf16* __restrict__ woffS,
    const float* __restrict__ b_off, float* __restrict__ om)
{
    __shared__ float sD[4][16][33];            // 8.4 KB

    const int tid = threadIdx.x, wv = tid >> 6, lane = tid & 63;
    const int g = (blockIdx.x & 7) * 64 + (blockIdx.x >> 3);   // XCD swizzle
    const int pixBase = g * 16;
    const int b = pixBase >> 12;
    const int hwBase = pixBase & 4095;
    const int h = hwBase >> 6, w0 = hwBase & 63;
    const int n15 = lane & 15, q4 = lane >> 4;

    f32x4 acc[2];
    #pragma unroll
    for (int j = 0; j < 2; j++) acc[j] = (f32x4){0.f, 0.f, 0.f, 0.f};

    const char* xb = (const char*)xT + ((size_t)b << 12) * 512;   // b*4096*512B

    for (int i = 0; i < 9; i++) {
        const int kb = wv * 9 + i;
        const int k = kb >> 2, cc = kb & 3;
        const int kh = k / 3, kw = k % 3;
        const int hh = h + kh - 1;
        const int ww = w0 + n15 + kw - 1;
        const bool valid = (hh >= 0) && (hh < HH) && (ww >= 0) && (ww < WW);
        const int hc = min(max(hh, 0), HH - 1);
        const int wc = min(max(ww, 0), WW - 1);
        const char* src = xb + (size_t)(hc * WW + wc) * 512 + (cc * 64 + q4 * 8) * 2;

        bf16x8 af[2];
        af[0] = *(const bf16x8*)src;
        af[1] = *(const bf16x8*)(src + 64);    // +32 channels
        if (!valid) {
            #pragma unroll
            for (int j = 0; j < 8; j++) { af[0][j] = (__bf16)0.f; af[1][j] = (__bf16)0.f; }
        }

        #pragma unroll
        for (int nf = 0; nf < 2; nf++) {
            #pragma unroll
            for (int ks = 0; ks < 2; ks++) {
                bf16x8 bfr = *(const bf16x8*)(woffS
                    + ((size_t)(((kb * 2 + ks) * 2 + nf) * 64 + lane)) * 8);
                acc[nf] = __builtin_amdgcn_mfma_f32_16x16x32_bf16(
                    af[ks], bfr, acc[nf], 0, 0, 0);
            }
        }
    }

    #pragma unroll
    for (int nf = 0; nf < 2; nf++)
        #pragma unroll
        for (int r = 0; r < 4; r++)
            sD[wv][q4 * 4 + r][nf * 16 + n15] = acc[nf][r];
    __syncthreads();

    for (int t = tid; t < OCH * 16; t += 256) {
        int oc = t >> 4, m = t & 15;
        float s = b_off[oc] + sD[0][m][oc] + sD[1][m][oc] + sD[2][m][oc] + sD[3][m][oc];
        om[(size_t)b * OCH * HW + oc * HW + hwBase + m] = s;
    }
}

// ---------------------------------------------------------------------------
// Kernel C: FUSED gather + MFMA GEMM + BN + SiLU. BARRIER-FREE main loop.
// M=16 px x N=256, grid 512 (2 blocks/CU). K split across the 4 waves
// (9 chunks each); each wave gathers its A-fragments DIRECTLY into registers
// from HWC xT (4 corner bf16x8 loads per 8 channels) and covers all 16
// N-frags (acc = 64 VGPRs). B in frag order, batches of 8. One LDS
// cross-wave reduction + BN/SiLU epilogue at the end.
// ---------------------------------------------------------------------------
__global__ __launch_bounds__(256) void fused_kernel(
    const __bf16* __restrict__ xT, const float* __restrict__ om,
    const __bf16* __restrict__ wbfS,
    const float* __restrict__ gamma, const float* __restrict__ beta,
    const float* __restrict__ rmean, const float* __restrict__ rvar,
    float* __restrict__ out)
{
    __shared__ int4   sO[9][16];         // 2.3 KB corner byte offsets
    __shared__ float4 sW[9][16];         // 2.3 KB corner weights
    __shared__ float  sC[2][16][260];    // 33.3 KB reduction buffer

    const int tid = threadIdx.x, wv = tid >> 6, lane = tid & 63;
    const int g = (blockIdx.x & 7) * 64 + (blockIdx.x >> 3);   // XCD swizzle
    const int pixBase = g * 16;
    const int b = pixBase >> 12;
    const int hwBase = pixBase & 4095;
    const int h = hwBase >> 6, w0 = hwBase & 63;

    // --- Phase 0: 4 clamped corner offsets + validity-folded weights ---
    const float* omb = om + (size_t)b * OCH * HW;
    if (tid < 144) {
        int k = tid >> 4, p = tid & 15;
        int hw = hwBase + p;
        float dy  = omb[(2 * k) * HW + hw];
        float dx  = omb[(2 * k + 1) * HW + hw];
        float mm  = omb[(18 + k) * HW + hw];
        mm = 1.f / (1.f + __expf(-mm));
        float py = (float)(h - 1 + k / 3) + dy;
        float px = (float)(w0 + p - 1 + k % 3) + dx;
        float y0f = floorf(py), x0f = floorf(px);
        float ly = py - y0f, lx = px - x0f;
        int y0 = (int)y0f, x0 = (int)x0f;
        int yc0 = min(max(y0, 0), HH - 1),     yc1 = min(max(y0 + 1, 0), HH - 1);
        int xc0 = min(max(x0, 0), WW - 1),     xc1 = min(max(x0 + 1, 0), WW - 1);
        float vy0 = (y0 >= 0 && y0 < HH) ? 1.f : 0.f;
        float vy1 = (y0 + 1 >= 0 && y0 + 1 < HH) ? 1.f : 0.f;
        float vx0 = (x0 >= 0 && x0 < WW) ? 1.f : 0.f;
        float vx1 = (x0 + 1 >= 0 && x0 + 1 < WW) ? 1.f : 0.f;
        sO[k][p] = (int4){(yc0 * WW + xc0) * 512, (yc0 * WW + xc1) * 512,
                          (yc1 * WW + xc0) * 512, (yc1 * WW + xc1) * 512};
        sW[k][p] = (float4){(1.f - ly) * (1.f - lx) * vy0 * vx0 * mm,
                            (1.f - ly) * lx         * vy0 * vx1 * mm,
                            ly         * (1.f - lx) * vy1 * vx0 * mm,
                            ly         * lx         * vy1 * vx1 * mm};
    }
    __syncthreads();

    const int n15 = lane & 15, q4 = lane >> 4;

    f32x4 acc[16];                       // 64 VGPRs
    #pragma unroll
    for (int j = 0; j < 16; j++) acc[j] = (f32x4){0.f, 0.f, 0.f, 0.f};

    const char* xb = (const char*)xT + ((size_t)b << 12) * 512;

    for (int i = 0; i < 9; i++) {
        const int kb = wv * 9 + i;
        const int k = kb >> 2, cc = kb & 3;
        const int4   O = sO[k][n15];
        const float4 W = sW[k][n15];
        const char* base = xb + (cc * 64 + q4 * 8) * 2;

        // --- gather A-fragments into registers (4 corner loads / 8 ch) ---
        bf16x8 af[2];
        #pragma unroll
        for (int ks = 0; ks < 2; ks++) {
            const char* bc = base + ks * 64;
            bf16x8 c00 = *(const bf16x8*)(bc + O.x);
            bf16x8 c01 = *(const bf16x8*)(bc + O.y);
            bf16x8 c10 = *(const bf16x8*)(bc + O.z);
            bf16x8 c11 = *(const bf16x8*)(bc + O.w);
            bf16x8 a;
            #pragma unroll
            for (int j = 0; j < 8; j++) {
                float v = W.x * (float)c00[j] + W.y * (float)c01[j]
                        + W.z * (float)c10[j] + W.w * (float)c11[j];
                a[j] = (__bf16)v;
            }
            af[ks] = a;
        }

        // --- B fragments (frag-ordered, coalesced) + MFMA, 2 batches of 8 ---
        #pragma unroll
        for (int half = 0; half < 2; half++) {
            bf16x8 bfr[8][2];
            #pragma unroll
            for (int nb = 0; nb < 8; nb++)
                #pragma unroll
                for (int ks = 0; ks < 2; ks++)
                    bfr[nb][ks] = *(const bf16x8*)(wbfS
                        + ((size_t)(((kb * 2 + ks) * 16 + half * 8 + nb) * 64 + lane)) * 8);
            #pragma unroll
            for (int nb = 0; nb < 8; nb++)
                #pragma unroll
                for (int ks = 0; ks < 2; ks++)
                    acc[half * 8 + nb] = __builtin_amdgcn_mfma_f32_16x16x32_bf16(
                        af[ks], bfr[nb][ks], acc[half * 8 + nb], 0, 0, 0);
        }
    }

    // --- Cross-wave K-reduction (2-stage) ---
    if (wv < 2) {
        #pragma unroll
        for (int nb = 0; nb < 16; nb++)
            #pragma unroll
            for (int r = 0; r < 4; r++)
                sC[wv][q4 * 4 + r][nb * 16 + n15] = acc[nb][r];
    }
    __syncthreads();
    if (wv >= 2) {
        #pragma unroll
        for (int nb = 0; nb < 16; nb++)
            #pragma unroll
            for (int r = 0; r < 4; r++)
                sC[wv - 2][q4 * 4 + r][nb * 16 + n15] += acc[nb][r];
    }
    __syncthreads();

    // --- Epilogue: BN + SiLU, coalesced (16 lanes = 16 consecutive px) ---
    const int px = tid & 15, og = tid >> 4;
    float* ob = out + ((size_t)b * C2 << 12) + hwBase + px;
    #pragma unroll
    for (int ii = 0; ii < 16; ii++) {
        int o = og * 16 + ii;
        float s = sC[0][px][o] + sC[1][px][o];
        float inv = gamma[o] * rsqrtf(rvar[o] + EPSV);
        float sh = beta[o] - rmean[o] * inv;
        float y = s * inv + sh;
        ob[(size_t)o << 12] = y * (1.f / (1.f + __expf(-y)));
    }
}

// ---------------------------------------------------------------------------
extern "C" void kernel_launch(void* const* d_in, const int* in_sizes, int n_in,
                              void* d_out, int out_size, void* d_ws, size_t ws_size,
                              hipStream_t stream) {
    const float* x      = (const float*)d_in[0];
    const float* w_off  = (const float*)d_in[1];
    const float* b_off  = (const float*)d_in[2];
    const float* w_dcn  = (const float*)d_in[3];
    const float* gamma  = (const float*)d_in[4];
    const float* beta   = (const float*)d_in[5];
    const float* rmean  = (const float*)d_in[6];
    const float* rvar   = (const float*)d_in[7];
    float* out = (float*)d_out;

    char* ws = (char*)d_ws;
    float*  om    = (float*)(ws + OM_OFF);
    __bf16* wbfS  = (__bf16*)(ws + WBF_OFF);
    __bf16* woffS = (__bf16*)(ws + WOFF_OFF);
    __bf16* xT    = (__bf16*)(ws + XT_OFF);

    xprep_kernel<<<512, 256, 0, stream>>>(x, xT);
    wprep_kernel<<<288, 256, 0, stream>>>(w_dcn, wbfS);
    wprep_off_kernel<<<36, 256, 0, stream>>>(w_off, woffS);
    offset_mfma_kernel<<<512, 256, 0, stream>>>(xT, woffS, b_off, om);
    fused_kernel<<<512, 256, 0, stream>>>(xT, om, wbfS, gamma, beta,
                                          rmean, rvar, out);
}